// Round 4
// baseline (442.564 us; speedup 1.0000x reference)
//
#include <hip/hip_runtime.h>
#include <cstddef>

// Problem constants
#define B_TOT   256
#define IN_CAPS 1152
#define KDIM    8
#define NJ      10
#define ND      16
#define JD      160                 // NJ*ND

// Tiling
#define BB      4                   // batches per block
#define ISPLIT  8                   // i-splits: isp == XCD id -> W slice L2-resident
#define IRANGE  (IN_CAPS/ISPLIT)    // 144
#define IPAR    16                  // i-parallel groups of 40 threads
#define NTHREADS 640                // 10 waves; 2 blocks/CU = 20 waves
#define CI      IPAR                // 16 i's per chunk (1 per i_par group)
#define NCHUNK  (IRANGE/CI)         // 9
#define NGROUP  (NCHUNK*2)          // 18 k-half groups (pipeline granule)
#define GRID    ((B_TOT/BB)*ISPLIT) // 512 blocks = 2/CU

__device__ __forceinline__ float dot4(float4 a, float4 b) {
    return a.x*b.x + a.y*b.y + a.z*b.z + a.w*b.w;
}
__device__ __forceinline__ float getc(const float4& v, int k) {
    switch (k) { case 0: return v.x; case 1: return v.y; case 2: return v.z; default: return v.w; }
}

// One routing iteration, R1 structure + software-pipelined W prefetch.
// W read directly global->reg (lanes (j,dq): j stride 512B, dq*16B contiguous ->
// every touched 64B line fully used; slice L2-resident per XCD). x staged once
// in LDS. Pipeline: wreg[2][4] double buffer, 4 float4 loads always in flight.
// !FIRST: c = softmax_j(u_hat . vsum); logits in regs via dq-quad shuffle,
// denominators via one wave through LDS (2 barriers/chunk). FIRST: no in-loop
// barriers at all.
template<bool FIRST, bool PARTIAL>
__global__ __launch_bounds__(NTHREADS, 5)   // cap VGPR at 102 so 2 blocks/CU fit
void iter_kernel(const float* __restrict__ x, const float* __restrict__ Wt,
                 const float* __restrict__ vsum, float* __restrict__ s_out)
{
    const int isp = blockIdx.x & (ISPLIT - 1);   // == XCD id (blockIdx % 8)
    const int g   = blockIdx.x >> 3;             // b-group 0..63
    const int b0  = g * BB;
    const int i_begin = isp * IRANGE;

    const int t = threadIdx.x;
    const int i_par = t / 40;              // 0..15
    const int r  = t - i_par * 40;
    const int j  = r >> 2;                 // 0..9
    const int dq = r & 3;                  // 0..3 (owns d = dq*4..dq*4+3)

    __shared__ float4 x_lds[BB][IRANGE][2];    // 18432 B: x[b][i][k] as 2 float4
    __shared__ float  logit_lds[BB][CI][NJ];   // 2560 B
    __shared__ float  denom_lds[BB][CI];       // 256 B (reciprocal)
    __shared__ float  s_red[BB][JD];           // 2560 B

    // stage ALL x for this block: 1152 float4, coalesced; zero s_red
    for (int f = t; f < BB * IRANGE * 2; f += NTHREADS) {
        const int bb = f / (IRANGE * 2);
        const int fi = f - bb * (IRANGE * 2);
        ((float4*)x_lds)[f] =
            ((const float4*)(x + ((size_t)(b0 + bb) * IN_CAPS + i_begin) * KDIM))[fi];
    }
    ((float*)s_red)[t] = 0.f;                  // NTHREADS == BB*JD exactly

    float4 vs[BB];
    if (!FIRST) {
        #pragma unroll
        for (int bb = 0; bb < BB; ++bb)
            vs[bb] = *(const float4*)(vsum + (size_t)(b0 + bb) * JD + j * ND + dq * 4);
    }
    __syncthreads();

    // W float4 index: i*320 + j*32 + (k)*4 + dq, k = h*4+kk
    const float4* Wf4 = (const float4*)Wt;
    const size_t wbase = (size_t)(i_begin + i_par) * 320 + j * 32 + dq;

    float4 wreg[2][4];
    #pragma unroll
    for (int kk = 0; kk < 4; ++kk) wreg[0][kk] = Wf4[wbase + kk * 4];   // group 0

    float4 s_acc[BB];
    #pragma unroll
    for (int bb = 0; bb < BB; ++bb) s_acc[bb] = make_float4(0.f, 0.f, 0.f, 0.f);
    float4 u[BB];

    #pragma unroll
    for (int gg = 0; gg < NGROUP; ++gg) {
        const int c = gg >> 1, h = gg & 1;
        // prefetch next k-half group (always 4 loads in flight during FMAs)
        if (gg + 1 < NGROUP) {
            const int c2 = (gg + 1) >> 1, h2 = (gg + 1) & 1;
            const size_t off = wbase + (size_t)c2 * (CI * 320) + h2 * 16;
            #pragma unroll
            for (int kk = 0; kk < 4; ++kk) wreg[(gg + 1) & 1][kk] = Wf4[off + kk * 4];
        }
        const int i_loc = c * CI + i_par;
        if (!FIRST && h == 0) {
            #pragma unroll
            for (int bb = 0; bb < BB; ++bb) u[bb] = make_float4(0.f, 0.f, 0.f, 0.f);
        }
        #pragma unroll
        for (int bb = 0; bb < BB; ++bb) {
            const float4 xk = x_lds[bb][i_loc][h];   // k-half of x, LDS broadcast
            float4& acc = FIRST ? s_acc[bb] : u[bb];
            #pragma unroll
            for (int kk = 0; kk < 4; ++kk) {
                const float xs = getc(xk, kk);
                acc.x += xs * wreg[gg & 1][kk].x;
                acc.y += xs * wreg[gg & 1][kk].y;
                acc.z += xs * wreg[gg & 1][kk].z;
                acc.w += xs * wreg[gg & 1][kk].w;
            }
        }
        if (!FIRST && h == 1) {
            // chunk epilogue: logits -> softmax -> weighted accumulate
            float lg[BB];
            #pragma unroll
            for (int bb = 0; bb < BB; ++bb) {
                float l = dot4(u[bb], vs[bb]);
                l += __shfl_xor(l, 1);         // sum over 4-lane d-quad
                l += __shfl_xor(l, 2);         // (quads are 4-aligned, never cross wave)
                lg[bb] = l;
                if (dq == 0) logit_lds[bb][i_par][j] = l;
            }
            __syncthreads();                   // (C) logits visible
            if (t < BB * CI) {                 // one wave: softmax denominators
                const int bb = t >> 4, il = t & 15;
                float den = 0.f;
                #pragma unroll
                for (int q = 0; q < NJ; ++q) den += __expf(logit_lds[bb][il][q]);
                denom_lds[bb][il] = 1.0f / den;   // |logit| small: no max-shift
            }
            __syncthreads();                   // (D) denominators visible
            #pragma unroll
            for (int bb = 0; bb < BB; ++bb) {
                const float cc = __expf(lg[bb]) * denom_lds[bb][i_par];
                s_acc[bb].x += cc * u[bb].x; s_acc[bb].y += cc * u[bb].y;
                s_acc[bb].z += cc * u[bb].z; s_acc[bb].w += cc * u[bb].w;
            }
        }
    }

    // block reduction over the 16 i_par groups via LDS atomics (once per kernel)
    const float premul = FIRST ? 0.1f : 1.0f;  // softmax(zeros) over 10 caps = 0.1
    #pragma unroll
    for (int bb = 0; bb < BB; ++bb) {
        float* dst = &s_red[bb][j * ND + dq * 4];
        atomicAdd(dst + 0, s_acc[bb].x * premul);
        atomicAdd(dst + 1, s_acc[bb].y * premul);
        atomicAdd(dst + 2, s_acc[bb].z * premul);
        atomicAdd(dst + 3, s_acc[bb].w * premul);
    }
    __syncthreads();
    {
        const int bb = t / JD, jd = t - bb * JD;   // 640 threads = 640 outputs
        const float val = s_red[bb][jd];
        if (PARTIAL)
            s_out[((size_t)isp * B_TOT + b0 + bb) * JD + jd] = val;  // unique owner
        else
            unsafeAtomicAdd(&s_out[(size_t)(b0 + bb) * JD + jd], val);
    }
}

// squash per (b,j): v = s * s2/(1+s2)/sqrt(s2+eps); 16-lane shuffle reduction.
// P partial slices summed first. mode 0: vsum = v; 1: vsum += v; 2: out = v.
template<int P>
__global__ __launch_bounds__(256)
void squash_kernel(float* __restrict__ s, float* __restrict__ vsum,
                   float* __restrict__ out, int mode)
{
    int idx = blockIdx.x * 256 + threadIdx.x;    // grid 160 -> 40960
    float sv = 0.f;
    #pragma unroll
    for (int p = 0; p < P; ++p) sv += s[(size_t)p * B_TOT * JD + idx];
    if (P == 1) s[idx] = 0.f;                    // atomic path: re-zero accumulator
    float sq = sv * sv;
    sq += __shfl_xor(sq, 1);
    sq += __shfl_xor(sq, 2);
    sq += __shfl_xor(sq, 4);
    sq += __shfl_xor(sq, 8);                     // sum over 16 d-lanes (16-aligned)
    float scale = sq / (1.0f + sq) / sqrtf(sq + 1e-7f);
    float v = sv * scale;
    if (mode == 0)      vsum[idx] = v;
    else if (mode == 1) vsum[idx] += v;
    else                out[idx] = v;
}

extern "C" void kernel_launch(void* const* d_in, const int* in_sizes, int n_in,
                              void* d_out, int out_size, void* d_ws, size_t ws_size,
                              hipStream_t stream)
{
    const float* x  = (const float*)d_in[0];   // [256,1152,8]
    const float* Wt = (const float*)d_in[1];   // [1152,10,8,16]
    float* out = (float*)d_out;                // [256,10,16]

    dim3 grid(GRID), blk(NTHREADS);
    dim3 sgrid((B_TOT * JD) / 256), sblk(256);

    const size_t slice = (size_t)B_TOT * JD;                    // 40960 floats
    const size_t need  = (ISPLIT + 1) * slice * sizeof(float);  // 1.47 MB

    if (ws_size >= need) {
        // partial-slice path: no global atomics, no memset, deterministic
        float* s_part = (float*)d_ws;              // [8][256][160]
        float* vsum   = s_part + (size_t)ISPLIT * slice;

        iter_kernel<true,  true><<<grid, blk, 0, stream>>>(x, Wt, nullptr, s_part);
        squash_kernel<ISPLIT><<<sgrid, sblk, 0, stream>>>(s_part, vsum, out, 0); // vsum = v1
        iter_kernel<false, true><<<grid, blk, 0, stream>>>(x, Wt, vsum, s_part);
        squash_kernel<ISPLIT><<<sgrid, sblk, 0, stream>>>(s_part, vsum, out, 1); // vsum = v1+v2
        iter_kernel<false, true><<<grid, blk, 0, stream>>>(x, Wt, vsum, s_part);
        squash_kernel<ISPLIT><<<sgrid, sblk, 0, stream>>>(s_part, vsum, out, 2); // out = v3
    } else {
        // fallback: single accumulator slice + global atomics
        float* s    = (float*)d_ws;
        float* vsum = s + slice;
        hipMemsetAsync(d_ws, 0, slice * sizeof(float), stream);

        iter_kernel<true,  false><<<grid, blk, 0, stream>>>(x, Wt, nullptr, s);
        squash_kernel<1><<<sgrid, sblk, 0, stream>>>(s, vsum, out, 0);
        iter_kernel<false, false><<<grid, blk, 0, stream>>>(x, Wt, vsum, s);
        squash_kernel<1><<<sgrid, sblk, 0, stream>>>(s, vsum, out, 1);
        iter_kernel<false, false><<<grid, blk, 0, stream>>>(x, Wt, vsum, s);
        squash_kernel<1><<<sgrid, sblk, 0, stream>>>(s, vsum, out, 2);
    }
}

// Round 5
// 261.020 us; speedup vs baseline: 1.6955x; 1.6955x over previous
//
#include <hip/hip_runtime.h>
#include <cstddef>

// Problem constants
#define B_TOT   256
#define IN_CAPS 1152
#define KDIM    8
#define NJ      10
#define ND      16
#define JD      160                  // NJ*ND

// Tiling
#define BB      4                    // batches per block
#define ISPLIT  8                    // i-splits; isp == blockIdx%8 -> XCD-aligned W slice
#define IRANGE  (IN_CAPS/ISPLIT)     // 144
#define NWAVES  12
#define NTHREADS (NWAVES*64)         // 768
#define CHUNK   (NWAVES*2)           // 24 i's per chunk (2 per wave)
#define NCHUNK  (IRANGE/CHUNK)       // 6
#define GRID    ((B_TOT/BB)*ISPLIT)  // 512 blocks = 2/CU

__device__ __forceinline__ float dot4(float4 a, float4 b) {
    return a.x*b.x + a.y*b.y + a.z*b.z + a.w*b.w;
}
__device__ __forceinline__ float getc(const float4& v, int k) {
    switch (k) { case 0: return v.x; case 1: return v.y; case 2: return v.z; default: return v.w; }
}

// One routing iteration with WAVE-LOCAL softmax: lane = jl*4+dq (jl<16, j=jl
// active for jl<10). One wave owns one i -> logits reduced over j via in-wave
// shfl_xor butterfly (stride 4/8/16/32). ZERO in-loop barriers. W read straight
// global->reg (40 lanes cover ten full 64B lines per instr; slice L2-resident
// per XCD). x staged once in LDS (broadcast reads). NSRC = # previous partial-s
// buffers: vsum is reconstructed in the prologue (fused squash), so the
// standalone mid-squash kernels disappear.
// NOTE: no conditional references / dynamic indexing anywhere (R4 spill bug).
template<int NSRC, bool PARTIAL>
__global__ __launch_bounds__(NTHREADS)
void iter_kernel(const float* __restrict__ x, const float* __restrict__ Wt,
                 const float* __restrict__ sA, const float* __restrict__ sB,
                 float* __restrict__ s_out)
{
    constexpr int PART = PARTIAL ? ISPLIT : 1;
    const int isp = blockIdx.x & (ISPLIT - 1);
    const int g   = blockIdx.x >> 3;
    const int b0  = g * BB;
    const int i_begin = isp * IRANGE;

    const int t    = threadIdx.x;
    const int wv   = t >> 6;         // wave 0..11
    const int lane = t & 63;
    const int jl   = lane >> 2;      // 0..15 (j = jl, active if jl < 10)
    const int dq   = lane & 3;       // d-quad: owns d = dq*4..dq*4+3
    const bool act = (jl < NJ);

    __shared__ float4 x_lds[BB * IRANGE * 2];  // 18432 B
    __shared__ float  s_red[BB * JD];          // 2560 B

    // stage ALL x for this block: 1152 float4, coalesced
    for (int f = t; f < BB * IRANGE * 2; f += NTHREADS) {
        const int bb = f / (IRANGE * 2);
        const int fi = f - bb * (IRANGE * 2);
        x_lds[f] = ((const float4*)(x + ((size_t)(b0 + bb) * IN_CAPS + i_begin) * KDIM))[fi];
    }
    if (t < BB * JD) s_red[t] = 0.f;

    // prologue: vsum (sum of squashed v's) from previous partial-s buffers
    float4 vs[BB];
    #pragma unroll
    for (int bb = 0; bb < BB; ++bb) vs[bb] = make_float4(0.f, 0.f, 0.f, 0.f);
    if (NSRC >= 1 && act) {
        #pragma unroll
        for (int bb = 0; bb < BB; ++bb) {
            float4 a = make_float4(0.f, 0.f, 0.f, 0.f);
            #pragma unroll
            for (int p = 0; p < PART; ++p) {
                const float4 q = *(const float4*)(sA + ((size_t)p * B_TOT + b0 + bb) * JD
                                                     + jl * ND + dq * 4);
                a.x += q.x; a.y += q.y; a.z += q.z; a.w += q.w;
            }
            float n = dot4(a, a);
            n += __shfl_xor(n, 1); n += __shfl_xor(n, 2);   // norm over 16 d (quad-local)
            const float sc = n / (1.f + n) / sqrtf(n + 1e-7f);
            vs[bb].x = a.x * sc; vs[bb].y = a.y * sc;
            vs[bb].z = a.z * sc; vs[bb].w = a.w * sc;
            if (NSRC == 2) {
                float4 b = make_float4(0.f, 0.f, 0.f, 0.f);
                #pragma unroll
                for (int p = 0; p < PART; ++p) {
                    const float4 q = *(const float4*)(sB + ((size_t)p * B_TOT + b0 + bb) * JD
                                                         + jl * ND + dq * 4);
                    b.x += q.x; b.y += q.y; b.z += q.z; b.w += q.w;
                }
                float n2 = dot4(b, b);
                n2 += __shfl_xor(n2, 1); n2 += __shfl_xor(n2, 2);
                const float sc2 = n2 / (1.f + n2) / sqrtf(n2 + 1e-7f);
                vs[bb].x += b.x * sc2; vs[bb].y += b.y * sc2;
                vs[bb].z += b.z * sc2; vs[bb].w += b.w * sc2;
            }
        }
    }
    __syncthreads();   // x_lds ready — the ONLY barrier before the epilogue

    float4 s_acc[BB];
    #pragma unroll
    for (int bb = 0; bb < BB; ++bb) s_acc[bb] = make_float4(0.f, 0.f, 0.f, 0.f);

    const float4* Wf4 = (const float4*)Wt;

    for (int c = 0; c < NCHUNK; ++c) {
        #pragma unroll
        for (int ii = 0; ii < 2; ++ii) {
            const int i_loc = c * CHUNK + wv * 2 + ii;
            float4 u[BB];
            #pragma unroll
            for (int bb = 0; bb < BB; ++bb) u[bb] = make_float4(0.f, 0.f, 0.f, 0.f);

            if (act) {
                // W row for (i, j=jl): 8 float4 loads, all independent
                const float4* wp = Wf4 + ((size_t)(i_begin + i_loc) * NJ + jl) * 32 + dq;
                float4 w[8];
                #pragma unroll
                for (int k = 0; k < 8; ++k) w[k] = wp[k * 4];
                #pragma unroll
                for (int bb = 0; bb < BB; ++bb) {
                    const float4 xk0 = x_lds[(bb * IRANGE + i_loc) * 2 + 0];  // LDS broadcast
                    const float4 xk1 = x_lds[(bb * IRANGE + i_loc) * 2 + 1];
                    #pragma unroll
                    for (int k = 0; k < 4; ++k) {
                        const float xs = getc(xk0, k);
                        u[bb].x += xs * w[k].x; u[bb].y += xs * w[k].y;
                        u[bb].z += xs * w[k].z; u[bb].w += xs * w[k].w;
                    }
                    #pragma unroll
                    for (int k = 0; k < 4; ++k) {
                        const float xs = getc(xk1, k);
                        u[bb].x += xs * w[4 + k].x; u[bb].y += xs * w[4 + k].y;
                        u[bb].z += xs * w[4 + k].z; u[bb].w += xs * w[4 + k].w;
                    }
                }
            }

            if (NSRC == 0) {
                #pragma unroll
                for (int bb = 0; bb < BB; ++bb) {
                    s_acc[bb].x += u[bb].x; s_acc[bb].y += u[bb].y;
                    s_acc[bb].z += u[bb].z; s_acc[bb].w += u[bb].w;
                }
            } else {
                // wave-local softmax over j: quad-reduce logit, then j-butterfly
                #pragma unroll
                for (int bb = 0; bb < BB; ++bb) {
                    float lg = dot4(u[bb], vs[bb]);          // u=vs=0 for jl>=10
                    lg += __shfl_xor(lg, 1); lg += __shfl_xor(lg, 2);
                    const float e = act ? __expf(lg) : 0.f;  // |logit| small: no max-shift
                    float den = e;
                    den += __shfl_xor(den, 4);  den += __shfl_xor(den, 8);
                    den += __shfl_xor(den, 16); den += __shfl_xor(den, 32);
                    const float cc = e / den;
                    s_acc[bb].x += cc * u[bb].x; s_acc[bb].y += cc * u[bb].y;
                    s_acc[bb].z += cc * u[bb].z; s_acc[bb].w += cc * u[bb].w;
                }
            }
        }
    }

    // block reduction over the 12 waves via LDS atomics (once per kernel)
    const float premul = (NSRC == 0) ? 0.1f : 1.0f;  // softmax(zeros) over 10 = 0.1
    if (act) {
        #pragma unroll
        for (int bb = 0; bb < BB; ++bb) {
            float* dst = &s_red[bb * JD + jl * ND + dq * 4];
            atomicAdd(dst + 0, s_acc[bb].x * premul);
            atomicAdd(dst + 1, s_acc[bb].y * premul);
            atomicAdd(dst + 2, s_acc[bb].z * premul);
            atomicAdd(dst + 3, s_acc[bb].w * premul);
        }
    }
    __syncthreads();
    if (t < BB * JD) {
        const int bb = t / JD, jd = t - bb * JD;
        const float val = s_red[t];
        if (PARTIAL)
            s_out[((size_t)isp * B_TOT + b0 + bb) * JD + jd] = val;   // unique owner
        else
            unsafeAtomicAdd(&s_out[(size_t)(b0 + bb) * JD + jd], val);
    }
}

// final squash: v = s * s2/(1+s2)/sqrt(s2+eps); 16-lane shuffle norm.
template<int P>
__global__ __launch_bounds__(256)
void squash_final(const float* __restrict__ s, float* __restrict__ out)
{
    const int idx = blockIdx.x * 256 + threadIdx.x;   // grid 160 -> 40960
    float sv = 0.f;
    #pragma unroll
    for (int p = 0; p < P; ++p) sv += s[(size_t)p * B_TOT * JD + idx];
    float sq = sv * sv;
    sq += __shfl_xor(sq, 1);
    sq += __shfl_xor(sq, 2);
    sq += __shfl_xor(sq, 4);
    sq += __shfl_xor(sq, 8);                          // sum over 16 d (16-aligned)
    const float scale = sq / (1.f + sq) / sqrtf(sq + 1e-7f);
    out[idx] = sv * scale;
}

extern "C" void kernel_launch(void* const* d_in, const int* in_sizes, int n_in,
                              void* d_out, int out_size, void* d_ws, size_t ws_size,
                              hipStream_t stream)
{
    const float* x  = (const float*)d_in[0];   // [256,1152,8]
    const float* Wt = (const float*)d_in[1];   // [1152,10,8,16]
    float* out = (float*)d_out;                // [256,10,16]

    dim3 grid(GRID), blk(NTHREADS);
    dim3 sgrid((B_TOT * JD) / 256), sblk(256);

    const size_t slice = (size_t)B_TOT * JD;            // 40960 floats
    const size_t psz   = (size_t)ISPLIT * slice;        // 327680 floats per buffer

    if (ws_size >= 3 * psz * sizeof(float)) {           // 3.93 MB: 3 partial buffers
        float* sA = (float*)d_ws;
        float* sB = sA + psz;
        float* sC = sB + psz;
        iter_kernel<0, true><<<grid, blk, 0, stream>>>(x, Wt, nullptr, nullptr, sA);
        iter_kernel<1, true><<<grid, blk, 0, stream>>>(x, Wt, sA, nullptr, sB);
        iter_kernel<2, true><<<grid, blk, 0, stream>>>(x, Wt, sA, sB, sC);
        squash_final<ISPLIT><<<sgrid, sblk, 0, stream>>>(sC, out);
    } else {                                            // fallback: atomic accumulation
        float* sA = (float*)d_ws;
        float* sB = sA + slice;
        float* sC = sB + slice;
        hipMemsetAsync(d_ws, 0, 3 * slice * sizeof(float), stream);
        iter_kernel<0, false><<<grid, blk, 0, stream>>>(x, Wt, nullptr, nullptr, sA);
        iter_kernel<1, false><<<grid, blk, 0, stream>>>(x, Wt, sA, nullptr, sB);
        iter_kernel<2, false><<<grid, blk, 0, stream>>>(x, Wt, sA, sB, sC);
        squash_final<1><<<sgrid, sblk, 0, stream>>>(sC, out);
    }
}